// Round 14
// baseline (142.926 us; speedup 1.0000x reference)
//
#include <hip/hip_runtime.h>
#include <math.h>

#define B_ 4
#define C_ 64
#define D_ 32
#define H_ 64
#define W_ 64
#define S_ (D_*H_*W_)      // 131072 spatial per (b,c)
#define S4_ (S_/4)         // 32768
#define HW_ (H_*W_)        // 4096

typedef float floatx4 __attribute__((ext_vector_type(4)));

// Conv halo tile (both channels): 10z x 14y x 70x, row stride 72.
#define TZ 10
#define TY 14
#define TXS 72
#define PLANE (TY*TXS)      // 1008
#define CHSZ (TZ*PLANE)     // 10080 floats per channel
#define HALO_N (2*TZ*TY*70) // 19600 logical fill elements

// Single fused kernel: 256 blocks (1/CU guaranteed by 81.8KB LDS) x 256 thr.
// Phase 1 (produce): block (b,dt,ht) computes xc (channel max/mean) for its
//   own 4D x 8H x 64W region from x, publishes with device-scope flag.
// Phase 2 (wait): spin on the 3x3 neighbor flags its conv halo needs.
// Phase 3 (consume): r10's halo-fill + kz-sharing conv + sigmoid + gating
//   stream; the gating x re-read is L3-hot from phase 1.
__global__ __launch_bounds__(256, 1) void fused_kernel(const float* __restrict__ x,
                                                       const float* __restrict__ cw,
                                                       const float* __restrict__ cb,
                                                       float* __restrict__ xc,
                                                       unsigned int* __restrict__ flags,
                                                       float* __restrict__ out) {
    __shared__ __align__(16) float tile[2 * CHSZ];   // 80.6 KB -> 1 block/CU
    __shared__ __align__(16) float wl[784];          // both ch, [kz][ky][8] 0-padded

    const int tid = threadIdx.x;
    const int b  = (int)blockIdx.z >> 3;
    const int dt = (int)blockIdx.z & 7;    // d-tile (0..7), 4 planes each
    const int ht = (int)blockIdx.y;        // h-tile (0..7), 8 rows each
    const int d0 = dt * 4;
    const int h0 = ht * 8;

    // -------- phase 1: produce xc for own region (2048 spatial = 512 f4) ----
    {
        const float4* xb = reinterpret_cast<const float4*>(x) + (size_t)b * C_ * S4_;
        float4* xcmax  = reinterpret_cast<float4*>(xc) + (size_t)(b * 2 + 0) * S4_;
        float4* xcmean = reinterpret_cast<float4*>(xc) + (size_t)(b * 2 + 1) * S4_;
        #pragma unroll
        for (int rep = 0; rep < 2; ++rep) {
            int p  = tid + rep * 256;           // 0..511
            int w4 = p & 15;
            int hh = (p >> 4) & 7;
            int dz = p >> 7;                    // 0..3
            int sp4 = (d0 + dz) * (HW_ / 4) + (h0 + hh) * (W_ / 4) + w4;
            const float4* xp = xb + sp4;
            float4 v = xp[0];
            float mx0 = v.x, mx1 = v.y, mx2 = v.z, mx3 = v.w;
            float sm0 = v.x, sm1 = v.y, sm2 = v.z, sm3 = v.w;
            #pragma unroll 8
            for (int c = 1; c < C_; ++c) {
                float4 t = xp[(size_t)c * S4_];
                mx0 = fmaxf(mx0, t.x); sm0 += t.x;
                mx1 = fmaxf(mx1, t.y); sm1 += t.y;
                mx2 = fmaxf(mx2, t.z); sm2 += t.z;
                mx3 = fmaxf(mx3, t.w); sm3 += t.w;
            }
            float4 a; a.x = mx0; a.y = mx1; a.z = mx2; a.w = mx3;
            xcmax[sp4] = a;
            const float inv = 1.0f / 64.0f;
            float4 m; m.x = sm0 * inv; m.y = sm1 * inv; m.z = sm2 * inv; m.w = sm3 * inv;
            xcmean[sp4] = m;
        }
    }
    __threadfence();                 // device-scope: xc visible across XCDs
    __syncthreads();                 // all threads' stores + fences done
    if (tid == 0)
        __hip_atomic_store(&flags[(int)blockIdx.z * 8 + ht], 1u,
                           __ATOMIC_RELEASE, __HIP_MEMORY_SCOPE_AGENT);

    // weights into LDS (overlaps the flag wait below)
    for (int idx = tid; idx < 784; idx += 256) {
        int ch = idx / 392;
        int r  = idx - ch * 392;
        int kz = r / 56;
        int r2 = r - kz * 56;
        int ky = r2 >> 3;
        int kw = r2 & 7;
        wl[idx] = (kw < 7) ? cw[ch * 343 + kz * 49 + ky * 7 + kw] : 0.f;
    }

    // -------- phase 2: wait on 3x3 neighbor flags (same b) ------------------
    if (tid < 9) {
        int nd = dt + (tid % 3) - 1;
        int nh = ht + (tid / 3) - 1;
        if (nd >= 0 && nd < 8 && nh >= 0 && nh < 8) {
            const unsigned int* f = &flags[(b * 8 + nd) * 8 + nh];
            while (__hip_atomic_load(f, __ATOMIC_ACQUIRE,
                                     __HIP_MEMORY_SCOPE_AGENT) == 0u)
                __builtin_amdgcn_s_sleep(2);
        }
    }
    __syncthreads();
    __threadfence();                 // acquire side: drop stale lines

    // -------- phase 3a: halo fill from xc, register-staged ------------------
    for (int base = tid; base < HALO_N; base += 256 * 8) {
        float sv[8];
        int   sa[8];
        #pragma unroll
        for (int k = 0; k < 8; ++k) {
            int idx = base + k * 256;
            sv[k] = 0.f;
            sa[k] = -1;
            if (idx < HALO_N) {
                int ch = idx / 9800;            // TZ*TY*70
                int r  = idx - ch * 9800;
                int z  = r / 980;               // TY*70
                int r2 = r - z * 980;
                int y  = r2 / 70;
                int xw = r2 - y * 70;
                sa[k] = ch * CHSZ + z * PLANE + y * TXS + xw;
                int gd = d0 + z - 3, gh = h0 + y - 3, gw = xw - 3;
                if ((unsigned)gd < (unsigned)D_ && (unsigned)gh < (unsigned)H_ &&
                    (unsigned)gw < (unsigned)W_)
                    sv[k] = xc[(size_t)(b * 2 + ch) * S_ + gd * HW_ + gh * W_ + gw];
            }
        }
        #pragma unroll
        for (int k = 0; k < 8; ++k)
            if (sa[k] >= 0) tile[sa[k]] = sv[k];
    }
    __syncthreads();

    // -------- phase 3b: conv, 2 D-outputs share every window read -----------
    const int w4 = tid & 15;            // w = 4*w4
    const int hh = (tid >> 4) & 7;      // h = h0 + hh
    const int dd = tid >> 7;            // 0..1
    const int dbase = d0 + 2 * dd;

    float acc0[4] = {0.f, 0.f, 0.f, 0.f};   // dout = dbase     (kz = z)
    float acc1[4] = {0.f, 0.f, 0.f, 0.f};   // dout = dbase + 1 (kz = z-1)
    for (int ch = 0; ch < 2; ++ch) {
        const float* tch = &tile[ch * CHSZ + 2 * dd * PLANE + w4 * 4];
        const float* wch = &wl[ch * 392];
        for (int ky = 0; ky < 7; ++ky) {
            const float* trow = tch + (hh + ky) * TXS;
            const float* wrow = wch + ky * 8;
            float wp[7];
            #pragma unroll
            for (int z = 0; z < 8; ++z) {
                const float* rp = trow + z * PLANE;
                float4 f0 = *reinterpret_cast<const float4*>(rp);
                float4 f1 = *reinterpret_cast<const float4*>(rp + 4);
                float2 f2 = *reinterpret_cast<const float2*>(rp + 8);
                float win[10] = {f0.x, f0.y, f0.z, f0.w,
                                 f1.x, f1.y, f1.z, f1.w, f2.x, f2.y};
                if (z >= 1) {
                    #pragma unroll
                    for (int kw = 0; kw < 7; ++kw) {
                        acc1[0] = fmaf(win[kw + 0], wp[kw], acc1[0]);
                        acc1[1] = fmaf(win[kw + 1], wp[kw], acc1[1]);
                        acc1[2] = fmaf(win[kw + 2], wp[kw], acc1[2]);
                        acc1[3] = fmaf(win[kw + 3], wp[kw], acc1[3]);
                    }
                }
                if (z < 7) {
                    float4 wa = *reinterpret_cast<const float4*>(wrow + z * 56);
                    float4 wb = *reinterpret_cast<const float4*>(wrow + z * 56 + 4);
                    float wc[7] = {wa.x, wa.y, wa.z, wa.w, wb.x, wb.y, wb.z};
                    #pragma unroll
                    for (int kw = 0; kw < 7; ++kw) {
                        acc0[0] = fmaf(win[kw + 0], wc[kw], acc0[0]);
                        acc0[1] = fmaf(win[kw + 1], wc[kw], acc0[1]);
                        acc0[2] = fmaf(win[kw + 2], wc[kw], acc0[2]);
                        acc0[3] = fmaf(win[kw + 3], wc[kw], acc0[3]);
                    }
                    #pragma unroll
                    for (int k = 0; k < 7; ++k) wp[k] = wc[k];
                }
            }
        }
    }

    // -------- sigmoid ----
    const float bias = cb[0];
    floatx4 s0, s1;
    s0.x = 1.0f / (1.0f + __expf(-(acc0[0] + bias)));
    s0.y = 1.0f / (1.0f + __expf(-(acc0[1] + bias)));
    s0.z = 1.0f / (1.0f + __expf(-(acc0[2] + bias)));
    s0.w = 1.0f / (1.0f + __expf(-(acc0[3] + bias)));
    s1.x = 1.0f / (1.0f + __expf(-(acc1[0] + bias)));
    s1.y = 1.0f / (1.0f + __expf(-(acc1[1] + bias)));
    s1.z = 1.0f / (1.0f + __expf(-(acc1[2] + bias)));
    s1.w = 1.0f / (1.0f + __expf(-(acc1[3] + bias)));

    // -------- phase 3c: gating stream (x re-read is L3-hot from phase 1) ----
    const int h = h0 + hh, w = w4 * 4;
    const size_t sp = (size_t)dbase * HW_ + (size_t)h * W_ + w;
    const float* xp = x + (size_t)b * C_ * S_ + sp;
    float* op = out + (size_t)b * C_ * S_ + sp;
    for (int c = 0; c < C_; c += 8) {
        floatx4 v[16];
        #pragma unroll
        for (int k = 0; k < 8; ++k) {
            const size_t off = (size_t)(c + k) * S_;
            v[2 * k]     = *reinterpret_cast<const floatx4*>(xp + off);
            v[2 * k + 1] = *reinterpret_cast<const floatx4*>(xp + off + HW_);
        }
        #pragma unroll
        for (int k = 0; k < 8; ++k) {
            const size_t off = (size_t)(c + k) * S_;
            *reinterpret_cast<floatx4*>(op + off)       = v[2 * k] * s0;
            *reinterpret_cast<floatx4*>(op + off + HW_) = v[2 * k + 1] * s1;
        }
    }
}

extern "C" void kernel_launch(void* const* d_in, const int* in_sizes, int n_in,
                              void* d_out, int out_size, void* d_ws, size_t ws_size,
                              hipStream_t stream) {
    const float* x  = (const float*)d_in[0];
    const float* cw = (const float*)d_in[1];   // [1][2][7][7][7]
    const float* cb = (const float*)d_in[2];   // [1]
    float* out = (float*)d_out;
    float* xc  = (float*)d_ws;                                   // 4 MiB
    unsigned int* flags =
        (unsigned int*)((char*)d_ws + (size_t)B_ * 2 * S_ * sizeof(float));

    // flags must be 0 at kernel start on EVERY call (graph-safe, deterministic)
    hipMemsetAsync(flags, 0, 256 * sizeof(unsigned int), stream);
    fused_kernel<<<dim3(1, H_ / 8, B_ * (D_ / 4)), dim3(256), 0, stream>>>(
        x, cw, cb, xc, flags, out);
}

// Round 15
// 87.221 us; speedup vs baseline: 1.6387x; 1.6387x over previous
//
#include <hip/hip_runtime.h>
#include <math.h>

#define B_ 4
#define C_ 64
#define D_ 32
#define H_ 64
#define W_ 64
#define S_ (D_*H_*W_)      // 131072 spatial per (b,c)
#define S4_ (S_/4)         // 32768
#define HW_ (H_*W_)        // 4096

typedef float floatx4 __attribute__((ext_vector_type(4)));

// ---------------- Kernel 1: channel-wise max & mean -> xc[B][2][D][H][W] ----
__global__ __launch_bounds__(256) void reduce_kernel(const float* __restrict__ x,
                                                     float* __restrict__ xc) {
    int i  = blockIdx.x * 256 + threadIdx.x;          // float4 index over B*S/4
    int b  = i >> 15;                                  // i / S4_
    int s4 = i & (S4_ - 1);
    const float4* x4 = reinterpret_cast<const float4*>(x) + (size_t)b * C_ * S4_ + s4;
    float4 v = x4[0];
    float mx0 = v.x, mx1 = v.y, mx2 = v.z, mx3 = v.w;
    float sm0 = v.x, sm1 = v.y, sm2 = v.z, sm3 = v.w;
    #pragma unroll 8
    for (int c = 1; c < C_; ++c) {
        float4 t = x4[(size_t)c * S4_];
        mx0 = fmaxf(mx0, t.x); sm0 += t.x;
        mx1 = fmaxf(mx1, t.y); sm1 += t.y;
        mx2 = fmaxf(mx2, t.z); sm2 += t.z;
        mx3 = fmaxf(mx3, t.w); sm3 += t.w;
    }
    float4* o = reinterpret_cast<float4*>(xc);
    float4 a; a.x = mx0; a.y = mx1; a.z = mx2; a.w = mx3;
    o[((size_t)b * 2 + 0) * S4_ + s4] = a;
    const float inv = 1.0f / 64.0f;
    float4 m; m.x = sm0 * inv; m.y = sm1 * inv; m.z = sm2 * inv; m.w = sm3 * inv;
    o[((size_t)b * 2 + 1) * S4_ + s4] = m;
}

// ------- Kernel 2 (fused): conv3d(2->1,k7,p3) + sigmoid + out = x*scale -----
// Round-10 structure (best measured: 90.1 us) with two changes:
//  1. Weights read directly from global cw with block-UNIFORM addresses ->
//     compiler emits s_load on the scalar pipe (K$-cached), removing 196 of
//     532 LDS reads per thread and the whole wl staging.
//  2. Gating chunk 0 (16 float4 loads, independent of conv) is issued BEFORE
//     the conv loop: HBM latency + first 64KB/CU of read stream overlap conv.
#define TZ 10
#define TY 14
#define TXS 72
#define PLANE (TY*TXS)      // 1008
#define CHSZ (TZ*PLANE)     // 10080 floats per channel
#define HALO_N (2*TZ*TY*70) // 19600 logical fill elements

__global__ __launch_bounds__(256, 1) void conv_gate_kernel(const float* __restrict__ xc,
                                                           const float* __restrict__ x,
                                                           const float* __restrict__ cw,
                                                           const float* __restrict__ cb,
                                                           float* __restrict__ out) {
    __shared__ __align__(16) float tile[2 * CHSZ];   // 80.64 KB -> 1 block/CU

    const int tid = threadIdx.x;
    const int b  = blockIdx.z >> 3;
    const int d0 = (blockIdx.z & 7) * 4;
    const int h0 = blockIdx.y * 8;

    const int w4 = tid & 15;            // w = 4*w4
    const int hh = (tid >> 4) & 7;      // h = h0 + hh
    const int dd = tid >> 7;            // 0..1
    const int dbase = d0 + 2 * dd;      // this thread's 2 output d-planes

    // halo fill, register-staged: 8 independent loads in flight per thread
    for (int base = tid; base < HALO_N; base += 256 * 8) {
        float sv[8];
        int   sa[8];
        #pragma unroll
        for (int k = 0; k < 8; ++k) {
            int idx = base + k * 256;
            sv[k] = 0.f;
            sa[k] = -1;
            if (idx < HALO_N) {
                int ch = idx / 9800;            // TZ*TY*70
                int r  = idx - ch * 9800;
                int z  = r / 980;               // TY*70
                int r2 = r - z * 980;
                int y  = r2 / 70;
                int xw = r2 - y * 70;
                sa[k] = ch * CHSZ + z * PLANE + y * TXS + xw;
                int gd = d0 + z - 3, gh = h0 + y - 3, gw = xw - 3;
                if ((unsigned)gd < (unsigned)D_ && (unsigned)gh < (unsigned)H_ &&
                    (unsigned)gw < (unsigned)W_)
                    sv[k] = xc[(size_t)(b * 2 + ch) * S_ + gd * HW_ + gh * W_ + gw];
            }
        }
        #pragma unroll
        for (int k = 0; k < 8; ++k)
            if (sa[k] >= 0) tile[sa[k]] = sv[k];
    }

    // gating chunk-0 preload (independent of conv): overlaps conv compute
    const int h = h0 + hh, w = w4 * 4;
    const size_t sp = (size_t)dbase * HW_ + (size_t)h * W_ + w;
    const float* xp = x + (size_t)b * C_ * S_ + sp;
    float* op = out + (size_t)b * C_ * S_ + sp;
    floatx4 v0[16];
    #pragma unroll
    for (int k = 0; k < 8; ++k) {
        const size_t off = (size_t)k * S_;
        v0[2 * k]     = *reinterpret_cast<const floatx4*>(xp + off);
        v0[2 * k + 1] = *reinterpret_cast<const floatx4*>(xp + off + HW_);
    }

    __syncthreads();   // halo visible

    // ---- conv: 2 D-outputs share every window read; weights via s_load ----
    float acc0[4] = {0.f, 0.f, 0.f, 0.f};   // dout = dbase     (kz = z)
    float acc1[4] = {0.f, 0.f, 0.f, 0.f};   // dout = dbase + 1 (kz = z-1)
    for (int ch = 0; ch < 2; ++ch) {
        const float* tch = &tile[ch * CHSZ + 2 * dd * PLANE + w4 * 4];
        const float* wch = cw + ch * 343;            // uniform -> scalar loads
        for (int ky = 0; ky < 7; ++ky) {
            const float* trow = tch + (hh + ky) * TXS;
            const float* wky  = wch + ky * 7;        // + kz*49 below
            float wp[7];
            #pragma unroll
            for (int z = 0; z < 8; ++z) {
                const float* rp = trow + z * PLANE;
                float4 f0 = *reinterpret_cast<const float4*>(rp);
                float4 f1 = *reinterpret_cast<const float4*>(rp + 4);
                float2 f2 = *reinterpret_cast<const float2*>(rp + 8);
                float win[10] = {f0.x, f0.y, f0.z, f0.w,
                                 f1.x, f1.y, f1.z, f1.w, f2.x, f2.y};
                if (z >= 1) {                   // dbase+1 uses previous plane's w
                    #pragma unroll
                    for (int kw = 0; kw < 7; ++kw) {
                        acc1[0] = fmaf(win[kw + 0], wp[kw], acc1[0]);
                        acc1[1] = fmaf(win[kw + 1], wp[kw], acc1[1]);
                        acc1[2] = fmaf(win[kw + 2], wp[kw], acc1[2]);
                        acc1[3] = fmaf(win[kw + 3], wp[kw], acc1[3]);
                    }
                }
                if (z < 7) {
                    const float* wr = wky + z * 49;  // uniform address
                    float wc[7];
                    #pragma unroll
                    for (int k = 0; k < 7; ++k) wc[k] = wr[k];
                    #pragma unroll
                    for (int kw = 0; kw < 7; ++kw) {
                        acc0[0] = fmaf(win[kw + 0], wc[kw], acc0[0]);
                        acc0[1] = fmaf(win[kw + 1], wc[kw], acc0[1]);
                        acc0[2] = fmaf(win[kw + 2], wc[kw], acc0[2]);
                        acc0[3] = fmaf(win[kw + 3], wc[kw], acc0[3]);
                    }
                    #pragma unroll
                    for (int k = 0; k < 7; ++k) wp[k] = wc[k];
                }
            }
        }
    }

    // ---- sigmoid in registers ----
    const float bias = cb[0];
    floatx4 s0, s1;
    s0.x = 1.0f / (1.0f + __expf(-(acc0[0] + bias)));
    s0.y = 1.0f / (1.0f + __expf(-(acc0[1] + bias)));
    s0.z = 1.0f / (1.0f + __expf(-(acc0[2] + bias)));
    s0.w = 1.0f / (1.0f + __expf(-(acc0[3] + bias)));
    s1.x = 1.0f / (1.0f + __expf(-(acc1[0] + bias)));
    s1.y = 1.0f / (1.0f + __expf(-(acc1[1] + bias)));
    s1.z = 1.0f / (1.0f + __expf(-(acc1[2] + bias)));
    s1.w = 1.0f / (1.0f + __expf(-(acc1[3] + bias)));

    // ---- gating stream: chunk 0 already in registers, then chunks 1..7 ----
    #pragma unroll
    for (int k = 0; k < 8; ++k) {
        const size_t off = (size_t)k * S_;
        *reinterpret_cast<floatx4*>(op + off)       = v0[2 * k] * s0;
        *reinterpret_cast<floatx4*>(op + off + HW_) = v0[2 * k + 1] * s1;
    }
    for (int c = 8; c < C_; c += 8) {
        floatx4 v[16];
        #pragma unroll
        for (int k = 0; k < 8; ++k) {
            const size_t off = (size_t)(c + k) * S_;
            v[2 * k]     = *reinterpret_cast<const floatx4*>(xp + off);
            v[2 * k + 1] = *reinterpret_cast<const floatx4*>(xp + off + HW_);
        }
        #pragma unroll
        for (int k = 0; k < 8; ++k) {
            const size_t off = (size_t)(c + k) * S_;
            *reinterpret_cast<floatx4*>(op + off)       = v[2 * k] * s0;
            *reinterpret_cast<floatx4*>(op + off + HW_) = v[2 * k + 1] * s1;
        }
    }
}

extern "C" void kernel_launch(void* const* d_in, const int* in_sizes, int n_in,
                              void* d_out, int out_size, void* d_ws, size_t ws_size,
                              hipStream_t stream) {
    const float* x  = (const float*)d_in[0];
    const float* cw = (const float*)d_in[1];   // [1][2][7][7][7]
    const float* cb = (const float*)d_in[2];   // [1]
    float* out = (float*)d_out;
    float* xc  = (float*)d_ws;                 // B*2*S floats (4 MiB)

    reduce_kernel<<<dim3((B_ * S4_) / 256), dim3(256), 0, stream>>>(x, xc);
    conv_gate_kernel<<<dim3(1, H_ / 8, B_ * (D_ / 4)), dim3(256), 0, stream>>>(
        xc, x, cw, cb, out);
}

// Round 16
// 85.205 us; speedup vs baseline: 1.6774x; 1.0237x over previous
//
#include <hip/hip_runtime.h>
#include <math.h>

#define B_ 4
#define C_ 64
#define D_ 32
#define H_ 64
#define W_ 64
#define S_ (D_*H_*W_)      // 131072 spatial per (b,c)
#define S4_ (S_/4)         // 32768
#define HW_ (H_*W_)        // 4096

typedef float floatx4 __attribute__((ext_vector_type(4)));

// ---------------- Kernel 1: channel-wise max & mean -> xc[B][2][D][H][W] ----
__global__ __launch_bounds__(256) void reduce_kernel(const float* __restrict__ x,
                                                     float* __restrict__ xc) {
    int i  = blockIdx.x * 256 + threadIdx.x;          // float4 index over B*S/4
    int b  = i >> 15;                                  // i / S4_
    int s4 = i & (S4_ - 1);
    const float4* x4 = reinterpret_cast<const float4*>(x) + (size_t)b * C_ * S4_ + s4;
    float4 v = x4[0];
    float mx0 = v.x, mx1 = v.y, mx2 = v.z, mx3 = v.w;
    float sm0 = v.x, sm1 = v.y, sm2 = v.z, sm3 = v.w;
    #pragma unroll 8
    for (int c = 1; c < C_; ++c) {
        float4 t = x4[(size_t)c * S4_];
        mx0 = fmaxf(mx0, t.x); sm0 += t.x;
        mx1 = fmaxf(mx1, t.y); sm1 += t.y;
        mx2 = fmaxf(mx2, t.z); sm2 += t.z;
        mx3 = fmaxf(mx3, t.w); sm3 += t.w;
    }
    float4* o = reinterpret_cast<float4*>(xc);
    float4 a; a.x = mx0; a.y = mx1; a.z = mx2; a.w = mx3;
    o[((size_t)b * 2 + 0) * S4_ + s4] = a;
    const float inv = 1.0f / 64.0f;
    float4 m; m.x = sm0 * inv; m.y = sm1 * inv; m.z = sm2 * inv; m.w = sm3 * inv;
    o[((size_t)b * 2 + 1) * S4_ + s4] = m;
}

// ------- Kernel 2 (fused): conv3d(2->1,k7,p3) + sigmoid + out = x*scale -----
// 512 blocks x 256 thr, tile 64W x 8H x 2D -> 63 KB LDS -> TWO blocks/CU
// resident (8 waves/CU, 2/SIMD): conv ds_read->FMA chains and fill/gate vmcnt
// waits finally have TLP cover; skewed blocks overlap conv with gate stream.
// Thread: ONE float4 output (w4, hh, dd). Weights via scalar loads (uniform
// addresses). Halo both channels: 2 x 8z x 14y x 70x, row stride 72.
#define ZT 8
#define YT 14
#define XS 72
#define PLANE (YT*XS)       // 1008
#define CHSZ (ZT*PLANE)     // 8064 floats per channel
#define HALO_N (2*ZT*YT*70) // 15680 logical fill elements

__global__ __launch_bounds__(256, 2) void conv_gate_kernel(const float* __restrict__ xc,
                                                           const float* __restrict__ x,
                                                           const float* __restrict__ cw,
                                                           const float* __restrict__ cb,
                                                           float* __restrict__ out) {
    __shared__ __align__(16) float tile[2 * CHSZ];   // 63 KB -> 2 blocks/CU

    const int tid = threadIdx.x;
    const int b  = blockIdx.z >> 4;            // 16 d-slabs of 2 planes
    const int d0 = (blockIdx.z & 15) * 2;
    const int h0 = blockIdx.y * 8;

    const int w4 = tid & 15;            // w = 4*w4
    const int hh = (tid >> 4) & 7;      // h = h0 + hh
    const int dd = tid >> 7;            // 0..1 -> d = d0 + dd

    // halo fill, register-staged: 8 independent loads in flight per thread
    for (int base = tid; base < HALO_N; base += 256 * 8) {
        float sv[8];
        int   sa[8];
        #pragma unroll
        for (int k = 0; k < 8; ++k) {
            int idx = base + k * 256;
            sv[k] = 0.f;
            sa[k] = -1;
            if (idx < HALO_N) {
                int ch = idx / 7840;            // ZT*YT*70
                int r  = idx - ch * 7840;
                int z  = r / 980;               // YT*70
                int r2 = r - z * 980;
                int y  = r2 / 70;
                int xw = r2 - y * 70;
                sa[k] = ch * CHSZ + z * PLANE + y * XS + xw;
                int gd = d0 + z - 3, gh = h0 + y - 3, gw = xw - 3;
                if ((unsigned)gd < (unsigned)D_ && (unsigned)gh < (unsigned)H_ &&
                    (unsigned)gw < (unsigned)W_)
                    sv[k] = xc[(size_t)(b * 2 + ch) * S_ + gd * HW_ + gh * W_ + gw];
            }
        }
        #pragma unroll
        for (int k = 0; k < 8; ++k)
            if (sa[k] >= 0) tile[sa[k]] = sv[k];
    }

    // gating chunk-0 preload (independent of conv): overlaps fill/conv
    const int h = h0 + hh, w = w4 * 4;
    const size_t sp = (size_t)(d0 + dd) * HW_ + (size_t)h * W_ + w;
    const float* xp = x + (size_t)b * C_ * S_ + sp;
    float* op = out + (size_t)b * C_ * S_ + sp;
    floatx4 v0[16];
    #pragma unroll
    for (int k = 0; k < 16; ++k)
        v0[k] = *reinterpret_cast<const floatx4*>(xp + (size_t)k * S_);

    __syncthreads();   // halo visible

    // ---- conv: 1 float4 output; weights via scalar loads ----
    float acc[4] = {0.f, 0.f, 0.f, 0.f};
    for (int ch = 0; ch < 2; ++ch) {
        const float* tch = &tile[ch * CHSZ + dd * PLANE + w4 * 4];
        const float* wch = cw + ch * 343;
        for (int ky = 0; ky < 7; ++ky) {
            const float* trow = tch + (hh + ky) * XS;
            const float* wky  = wch + ky * 7;
            #pragma unroll
            for (int kz = 0; kz < 7; ++kz) {
                const float* rp = trow + kz * PLANE;
                float4 f0 = *reinterpret_cast<const float4*>(rp);
                float4 f1 = *reinterpret_cast<const float4*>(rp + 4);
                float2 f2 = *reinterpret_cast<const float2*>(rp + 8);
                float win[10] = {f0.x, f0.y, f0.z, f0.w,
                                 f1.x, f1.y, f1.z, f1.w, f2.x, f2.y};
                const float* wr = wky + kz * 49;     // uniform -> s_load
                float wc[7];
                #pragma unroll
                for (int k = 0; k < 7; ++k) wc[k] = wr[k];
                #pragma unroll
                for (int kw = 0; kw < 7; ++kw) {
                    acc[0] = fmaf(win[kw + 0], wc[kw], acc[0]);
                    acc[1] = fmaf(win[kw + 1], wc[kw], acc[1]);
                    acc[2] = fmaf(win[kw + 2], wc[kw], acc[2]);
                    acc[3] = fmaf(win[kw + 3], wc[kw], acc[3]);
                }
            }
        }
    }

    // ---- sigmoid ----
    const float bias = cb[0];
    floatx4 s0;
    s0.x = 1.0f / (1.0f + __expf(-(acc[0] + bias)));
    s0.y = 1.0f / (1.0f + __expf(-(acc[1] + bias)));
    s0.z = 1.0f / (1.0f + __expf(-(acc[2] + bias)));
    s0.w = 1.0f / (1.0f + __expf(-(acc[3] + bias)));

    // ---- gating stream: 64 channels, chunk 0 already in registers ----
    #pragma unroll
    for (int k = 0; k < 16; ++k)
        *reinterpret_cast<floatx4*>(op + (size_t)k * S_) = v0[k] * s0;
    for (int c = 16; c < C_; c += 16) {
        floatx4 v[16];
        #pragma unroll
        for (int k = 0; k < 16; ++k)
            v[k] = *reinterpret_cast<const floatx4*>(xp + (size_t)(c + k) * S_);
        #pragma unroll
        for (int k = 0; k < 16; ++k)
            *reinterpret_cast<floatx4*>(op + (size_t)(c + k) * S_) = v[k] * s0;
    }
}

extern "C" void kernel_launch(void* const* d_in, const int* in_sizes, int n_in,
                              void* d_out, int out_size, void* d_ws, size_t ws_size,
                              hipStream_t stream) {
    const float* x  = (const float*)d_in[0];
    const float* cw = (const float*)d_in[1];   // [1][2][7][7][7]
    const float* cb = (const float*)d_in[2];   // [1]
    float* out = (float*)d_out;
    float* xc  = (float*)d_ws;                 // B*2*S floats (4 MiB)

    reduce_kernel<<<dim3((B_ * S4_) / 256), dim3(256), 0, stream>>>(x, xc);
    conv_gate_kernel<<<dim3(1, H_ / 8, B_ * (D_ / 2)), dim3(256), 0, stream>>>(
        xc, x, cw, cb, out);
}